// Round 7
// baseline (261.829 us; speedup 1.0000x reference)
//
#include <hip/hip_runtime.h>

// Conv2d via implicit-GEMM MFMA: input (64,8,256,256) f32, filter (8,8,3,3)
// OIHW, VALID, stride 1 -> out (64,8,254,254) f32.
//
// mfma_f32_16x16x32_f16: M = out-channel m (8 valid of 16), N = 16 px,
// K = 96 = 3 chunks of 32. k-slot (g=lane>>4, j): q = kk*4+g (q=r*3+s,
// valid q<=8), c = j. A zeroed for q>8 / m>=8. Same convention as the
// refcheck-passed round-2..6 kernels; R5 staging/swizzle kept verbatim.
//
// Round-7 change: TRUE 4-blocks/CU residency. R6's occupancy bet never ran:
// 4 blocks/CU of work behind a 3/CU residency cap -> 12-wave phase + lone-
// block tail, time-average ~= R5's 8 waves (hence identical perf). Fix the
// footprint to EXACTLY 40960 B = 160KB/4:
//  - one LDS arena: 2-slot input ring 32768 B (overflow pad dropped; the
//    xg=15 overflow read lands in the out-buffer region = garbage feeding
//    only store-masked px>=254) + per-wave out-buf 2 KB (8 m x 64 px,
//    flushed in 4 batches; 2x b128 conflict-free reads, dense float2 stores).
// Grid 1024 = exactly 4 resident/CU, zero tail. Nothing else changed.

typedef _Float16 half8 __attribute__((ext_vector_type(8)));
typedef float floatx4 __attribute__((ext_vector_type(4)));

#define SLOT_H 8192   // halfs per 4-row slot (4 rows * 256 px * 8 c = 16 KB)

__global__ __launch_bounds__(256, 4)
void conv2d_mfma_kernel(const float* __restrict__ inp,
                        const float* __restrict__ filt,
                        float* __restrict__ out) {
    // one arena, exactly 40960 B: [0,16384) halfs = input ring,
    // [16384,20480) halfs = out-buffer (as float[2048]: 512 per wave)
    __shared__ __align__(16) _Float16 smem[20480];
    float* s_out = reinterpret_cast<float*>(&smem[16384]);

    const int tid    = threadIdx.x;
    const int ystrip = blockIdx.x * 16;   // 0,16,...,240
    const int n      = blockIdx.y;

    const float* in_n  = inp + (size_t)n * (8 * 256 * 256);
    float*       out_n = out + (size_t)n * (8 * 254 * 254);

    const int lane = tid & 63;
    const int w    = tid >> 6;    // wave 0..3 (staging row / output row owner)
    const int lx   = lane & 15;   // A: row m ; B/D: col pixel
    const int g    = lane >> 4;   // k-slot group / D row group
    const int lx4  = lane;        // staging: float4 index within row

    // ---- A-fragments + swizzled per-lane read offsets (verbatim R5/R6) ----
    half8 afrag[3];
    int   roff[3];
    int   loH[3][4];   // half-index offset within a row, per kk per (xg&3)
    #pragma unroll
    for (int kk = 0; kk < 3; ++kk) {
        int q  = kk * 4 + g;                 // 0..11
        int qa = q > 8 ? 8 : q;              // clamp for address only
        roff[kk] = qa / 3;
        int soff = qa - roff[kk] * 3;
        int q0   = lx + soff;                // 0..17: pixel offset in 16-grp
        int e    = (q0 & 3) ^ ((q0 >> 2) & 3);
        int q0b  = q0 >> 4;                  // crosses into next group
        int baseH = (q0 >> 2) * 32;          // quad slot, halfs
        #pragma unroll
        for (int j = 0; j < 4; ++j)          // j = xg & 3
            loH[kk][j] = baseH + ((e ^ ((j + q0b) & 3)) << 3);
        half8 a = {};
        if (q <= 8 && lx < 8) {
            #pragma unroll
            for (int j = 0; j < 8; ++j)      // filt[m][c][r][s] = m*72+c*9+q
                a[j] = (_Float16)filt[lx * 72 + j * 9 + q];
        }
        afrag[kk] = a;
    }

    // ---- staging (verbatim R5/R6 mechanics, chunk = 4 strip rows) ----
    auto load_chunk = [&](int ck, float4* dst) {
        const int iy = ystrip + ck * 4 + w;
        if (iy < 256) {
            const float* p = in_n + iy * 256 + lx4 * 4;
            #pragma unroll
            for (int c = 0; c < 8; ++c)
                dst[c] = *reinterpret_cast<const float4*>(p + c * 65536);
        } else {
            #pragma unroll
            for (int c = 0; c < 8; ++c) dst[c] = make_float4(0.f,0.f,0.f,0.f);
        }
    };
    auto write_chunk = [&](int ck, const float4* src) {
        _Float16* base = &smem[(ck & 1) * SLOT_H + w * 2048 + lx4 * 32];
        const int sw = (lx4 & 3) ^ ((lx4 >> 2) & 3);
        #pragma unroll
        for (int i = 0; i < 4; ++i) {
            half8 h;
            #pragma unroll
            for (int c = 0; c < 8; ++c) h[c] = (_Float16)src[c][i];
            *reinterpret_cast<half8*>(base + ((i ^ sw) << 3)) = h;
        }
    };

    float4 vv[8], vv2[8];
    load_chunk(0, vv);
    load_chunk(1, vv2);      // both prologue loads in flight together
    write_chunk(0, vv);
    write_chunk(1, vv2);
    __syncthreads();

    // ---- pipelined y-walk: 4 steps of 4 output rows ----
    for (int t = 0; t < 4; ++t) {
        if (t < 3) load_chunk(t + 2, vv);    // fly under compute(t)
        __builtin_amdgcn_sched_barrier(0);   // pin load issue before compute

        const int ro = t * 4 + w;            // this wave's strip-local row
        const int oy = ystrip + ro;

        int ab[3][4];
        #pragma unroll
        for (int kk = 0; kk < 3; ++kk) {
            int L   = ro + roff[kk];         // input row needed (0..17)
            int rbH = ((L >> 2) & 1) * SLOT_H + (L & 3) * 2048;
            #pragma unroll
            for (int j = 0; j < 4; ++j) ab[kk][j] = rbH + loH[kk][j];
        }

        const bool do_out = (g < 2) && (oy < 254);
        #pragma unroll
        for (int b = 0; b < 4; ++b) {        // 4 px-batches of 64 px
            #pragma unroll
            for (int xgl = 0; xgl < 4; ++xgl) {
                const int xg = b * 4 + xgl;
                floatx4 acc = {0.f, 0.f, 0.f, 0.f};
                #pragma unroll
                for (int kk = 0; kk < 3; ++kk) {
                    const half8 bb = *reinterpret_cast<const half8*>(
                        &smem[ab[kk][xg & 3] + xg * 128]);
                    acc = __builtin_amdgcn_mfma_f32_16x16x32_f16(
                              afrag[kk], bb, acc, 0, 0, 0);
                }
                // D: col = lane&15 (px), row = g*4+i (m; valid g<2)
                if (do_out) {
                    #pragma unroll
                    for (int i = 0; i < 4; ++i)
                        s_out[w * 512 + (g * 4 + i) * 64 + xgl * 16 + lx]
                            = acc[i];        // 2-way bank (g0/g1) = free
                }
            }
            // flush batch: 2 conflict-free b128 reads -> dense float2 stores
            if (oy < 254) {
                #pragma unroll
                for (int p = 0; p < 2; ++p) {
                    float4 q4 = *reinterpret_cast<const float4*>(
                        &s_out[w * 512 + p * 256 + lane * 4]);
                    const int m  = p * 4 + (lane >> 4);
                    const int px = b * 64 + (lane & 15) * 4;   // <= 252
                    float* op = out_n + (size_t)m * 64516 + oy * 254 + px;
                    *reinterpret_cast<float2*>(op) = make_float2(q4.x, q4.y);
                    if (px + 2 < 254)        // masks only px=252's upper pair
                        *reinterpret_cast<float2*>(op + 2)
                            = make_float2(q4.z, q4.w);
                }
            }
        }

        if (t < 3) {
            __syncthreads();                 // all waves done reading slot t&1
            write_chunk(t + 2, vv);          // overwrite slot t&1
            __syncthreads();                 // slot ready for compute(t+1)
        }
    }
}

extern "C" void kernel_launch(void* const* d_in, const int* in_sizes, int n_in,
                              void* d_out, int out_size, void* d_ws, size_t ws_size,
                              hipStream_t stream) {
    const float* inp  = (const float*)d_in[0];   // (64,8,256,256)
    const float* filt = (const float*)d_in[1];   // (8,8,3,3)
    float* outp = (float*)d_out;                 // (64,8,254,254)

    dim3 grid(16, 64, 1);
    dim3 block(256);
    conv2d_mfma_kernel<<<grid, block, 0, stream>>>(inp, filt, outp);
}

// Round 8
// 261.207 us; speedup vs baseline: 1.0024x; 1.0024x over previous
//
#include <hip/hip_runtime.h>

// Conv2d via implicit-GEMM MFMA: input (64,8,256,256) f32, filter (8,8,3,3)
// OIHW, VALID, stride 1 -> out (64,8,254,254) f32.
//
// mfma_f32_16x16x32_f16: M = out-channel m (8 valid of 16), N = 16 px,
// K = 96 = 3 chunks of 32. k-slot (g=lane>>4, j): q = kk*4+g (q=r*3+s,
// valid q<=8), c = j. A zeroed for q>8 / m>=8. Same convention as the
// refcheck-passed round-2..7 kernels; R5 staging/swizzle kept verbatim.
//
// Round-8 change: DE-PHASE the machine-wide HBM address stream. R2..R7 all
// plateau at ~2 TB/s with every pipe idle; instantaneous load addresses are
// n*2^21 + c*2^18 + row*2^10 + lane*16 with ALL strip bases == 0 mod 16 KB
// and all blocks phase-locked (same-length steps, launched together), so
// address bits 12-13 (row mod 16) take ONE value machine-wide at any
// instant -> ~1/4 of HBM channel/bank granules active if the interleave
// selector reaches those bits. Fix: offset each image's strip grid by
// 4*(n&3) rows (17 ragged strips/image; empty/partial edge blocks). Strip
// bases now cover {0,4,8,12} KB mod 16 KB uniformly -> all 16 row-phases
// in flight at every instant. Traffic, LDS (40960 B, 4 blocks/CU), and the
// compute/staging machinery are unchanged from R7.

typedef _Float16 half8 __attribute__((ext_vector_type(8)));
typedef float floatx4 __attribute__((ext_vector_type(4)));

#define SLOT_H 8192   // halfs per 4-row slot (4 rows * 256 px * 8 c = 16 KB)

__global__ __launch_bounds__(256, 4)
void conv2d_mfma_kernel(const float* __restrict__ inp,
                        const float* __restrict__ filt,
                        float* __restrict__ out) {
    // one arena, exactly 40960 B: [0,16384) halfs = input ring,
    // [16384,20480) halfs = out-buffer (as float[2048]: 512 per wave)
    __shared__ __align__(16) _Float16 smem[20480];
    float* s_out = reinterpret_cast<float*>(&smem[16384]);

    const int tid = threadIdx.x;
    const int k   = blockIdx.x;          // strip index 0..16 (ragged)
    const int n   = blockIdx.y;

    // per-image row-phase offset: breaks the mod-16KB congruence of strips
    const int off = 4 * (n & 3);
    const int ys0 = 16 * (k - 1) + off;
    const int ye  = min(254, ys0 + 16);  // block covers output rows [ys, ye)
    const int ys  = max(0, ys0);
    if (ys >= ye) return;                // block-uniform: barrier-safe
    const int nsteps = (ye - ys + 3) >> 2;

    const float* in_n  = inp + (size_t)n * (8 * 256 * 256);
    float*       out_n = out + (size_t)n * (8 * 254 * 254);

    const int lane = tid & 63;
    const int w    = tid >> 6;    // wave 0..3 (staging row / output row owner)
    const int lx   = lane & 15;   // A: row m ; B/D: col pixel
    const int g    = lane >> 4;   // k-slot group / D row group
    const int lx4  = lane;        // staging: float4 index within row

    // ---- A-fragments + swizzled per-lane read offsets (verbatim R5..R7) ----
    half8 afrag[3];
    int   roff[3];
    int   loH[3][4];   // half-index offset within a row, per kk per (xg&3)
    #pragma unroll
    for (int kk = 0; kk < 3; ++kk) {
        int q  = kk * 4 + g;                 // 0..11
        int qa = q > 8 ? 8 : q;              // clamp for address only
        roff[kk] = qa / 3;
        int soff = qa - roff[kk] * 3;
        int q0   = lx + soff;                // 0..17: pixel offset in 16-grp
        int e    = (q0 & 3) ^ ((q0 >> 2) & 3);
        int q0b  = q0 >> 4;                  // crosses into next group
        int baseH = (q0 >> 2) * 32;          // quad slot, halfs
        #pragma unroll
        for (int j = 0; j < 4; ++j)          // j = xg & 3
            loH[kk][j] = baseH + ((e ^ ((j + q0b) & 3)) << 3);
        half8 a = {};
        if (q <= 8 && lx < 8) {
            #pragma unroll
            for (int j = 0; j < 8; ++j)      // filt[m][c][r][s] = m*72+c*9+q
                a[j] = (_Float16)filt[lx * 72 + j * 9 + q];
        }
        afrag[kk] = a;
    }

    // ---- staging (verbatim mechanics, chunk ck = block rows ys+4ck..+3) ----
    auto load_chunk = [&](int ck, float4* dst) {
        const int iy = ys + ck * 4 + w;
        if (iy < 256) {
            const float* p = in_n + iy * 256 + lx4 * 4;
            #pragma unroll
            for (int c = 0; c < 8; ++c)
                dst[c] = *reinterpret_cast<const float4*>(p + c * 65536);
        } else {
            #pragma unroll
            for (int c = 0; c < 8; ++c) dst[c] = make_float4(0.f,0.f,0.f,0.f);
        }
    };
    auto write_chunk = [&](int ck, const float4* src) {
        _Float16* base = &smem[(ck & 1) * SLOT_H + w * 2048 + lx4 * 32];
        const int sw = (lx4 & 3) ^ ((lx4 >> 2) & 3);
        #pragma unroll
        for (int i = 0; i < 4; ++i) {
            half8 h;
            #pragma unroll
            for (int c = 0; c < 8; ++c) h[c] = (_Float16)src[c][i];
            *reinterpret_cast<half8*>(base + ((i ^ sw) << 3)) = h;
        }
    };

    float4 vv[8], vv2[8];
    load_chunk(0, vv);
    load_chunk(1, vv2);      // both prologue loads in flight together
    write_chunk(0, vv);
    write_chunk(1, vv2);
    __syncthreads();

    // ---- pipelined y-walk: nsteps (1..4) steps of 4 output rows ----
    for (int t = 0; t < nsteps; ++t) {
        if (t + 1 < nsteps) load_chunk(t + 2, vv);   // fly under compute(t)
        __builtin_amdgcn_sched_barrier(0);   // pin load issue before compute

        const int ro = t * 4 + w;            // this wave's block-local row
        const int oy = ys + ro;

        int ab[3][4];
        #pragma unroll
        for (int kk = 0; kk < 3; ++kk) {
            int L   = ro + roff[kk];         // block-local input row
            int rbH = ((L >> 2) & 1) * SLOT_H + (L & 3) * 2048;
            #pragma unroll
            for (int j = 0; j < 4; ++j) ab[kk][j] = rbH + loH[kk][j];
        }

        const bool do_out = (g < 2) && (oy < 254);
        #pragma unroll
        for (int b = 0; b < 4; ++b) {        // 4 px-batches of 64 px
            #pragma unroll
            for (int xgl = 0; xgl < 4; ++xgl) {
                const int xg = b * 4 + xgl;
                floatx4 acc = {0.f, 0.f, 0.f, 0.f};
                #pragma unroll
                for (int kk = 0; kk < 3; ++kk) {
                    const half8 bb = *reinterpret_cast<const half8*>(
                        &smem[ab[kk][xg & 3] + xg * 128]);
                    acc = __builtin_amdgcn_mfma_f32_16x16x32_f16(
                              afrag[kk], bb, acc, 0, 0, 0);
                }
                // D: col = lane&15 (px), row = g*4+i (m; valid g<2)
                if (do_out) {
                    #pragma unroll
                    for (int i = 0; i < 4; ++i)
                        s_out[w * 512 + (g * 4 + i) * 64 + xgl * 16 + lx]
                            = acc[i];        // 2-way bank (g0/g1) = free
                }
            }
            // flush batch: 2 conflict-free b128 reads -> dense float2 stores
            if (oy < 254) {
                #pragma unroll
                for (int p = 0; p < 2; ++p) {
                    float4 q4 = *reinterpret_cast<const float4*>(
                        &s_out[w * 512 + p * 256 + lane * 4]);
                    const int m  = p * 4 + (lane >> 4);
                    const int px = b * 64 + (lane & 15) * 4;   // <= 252
                    float* op = out_n + (size_t)m * 64516 + oy * 254 + px;
                    *reinterpret_cast<float2*>(op) = make_float2(q4.x, q4.y);
                    if (px + 2 < 254)        // masks only px=252's upper pair
                        *reinterpret_cast<float2*>(op + 2)
                            = make_float2(q4.z, q4.w);
                }
            }
        }

        if (t + 1 < nsteps) {
            __syncthreads();                 // all waves done reading slot t&1
            write_chunk(t + 2, vv);          // overwrite slot t&1
            __syncthreads();                 // slot ready for compute(t+1)
        }
    }
}

extern "C" void kernel_launch(void* const* d_in, const int* in_sizes, int n_in,
                              void* d_out, int out_size, void* d_ws, size_t ws_size,
                              hipStream_t stream) {
    const float* inp  = (const float*)d_in[0];   // (64,8,256,256)
    const float* filt = (const float*)d_in[1];   // (8,8,3,3)
    float* outp = (float*)d_out;                 // (64,8,254,254)

    dim3 grid(17, 64, 1);
    dim3 block(256);
    conv2d_mfma_kernel<<<grid, block, 0, stream>>>(inp, filt, outp);
}